// Round 1
// baseline (293.808 us; speedup 1.0000x reference)
//
#include <hip/hip_runtime.h>

typedef __attribute__((ext_vector_type(4))) int int4v;

// --- async global->LDS, 16B per lane, wave-uniform LDS base ---
__device__ __forceinline__ void async_ld16(const void* g, void* l) {
  __builtin_amdgcn_global_load_lds(
      (const __attribute__((address_space(1))) void*)g,
      (__attribute__((address_space(3))) void*)l,
      16, 0, 0);
}

// ---------------- 1) absmax over x ----------------
__global__ void absmax_kernel(const float* __restrict__ x,
                              unsigned int* __restrict__ out_bits, int n4) {
  const float4* x4 = (const float4*)x;
  float m = 0.0f;
  for (int i = blockIdx.x * blockDim.x + threadIdx.x; i < n4;
       i += gridDim.x * blockDim.x) {
    float4 v = x4[i];
    m = fmaxf(m, fabsf(v.x));
    m = fmaxf(m, fabsf(v.y));
    m = fmaxf(m, fabsf(v.z));
    m = fmaxf(m, fabsf(v.w));
  }
#pragma unroll
  for (int off = 32; off > 0; off >>= 1)
    m = fmaxf(m, __shfl_down(m, off, 64));
  __shared__ float wmax[4];
  const int wid = threadIdx.x >> 6;
  if ((threadIdx.x & 63) == 0) wmax[wid] = m;
  __syncthreads();
  if (threadIdx.x == 0) {
    float bm = fmaxf(fmaxf(wmax[0], wmax[1]), fmaxf(wmax[2], wmax[3]));
    // all values non-negative -> uint bit compare == float compare
    atomicMax(out_bits, __float_as_uint(bm));
  }
}

// ---------------- 2) quantize x -> int8 (packed 4/int) ----------------
__global__ void quant_x_kernel(const float* __restrict__ x,
                               const unsigned int* __restrict__ max_bits,
                               int* __restrict__ qx, int n4) {
  const float scale = __uint_as_float(*max_bits) / 127.0f;  // exact same as ref
  int i = blockIdx.x * blockDim.x + threadIdx.x;
  if (i >= n4) return;
  float4 v = ((const float4*)x)[i];
  // true IEEE division + rint (half-to-even) to match jnp.round(t/scale)
  int q0 = (int)fminf(fmaxf(rintf(v.x / scale), -127.0f), 127.0f);
  int q1 = (int)fminf(fmaxf(rintf(v.y / scale), -127.0f), 127.0f);
  int q2 = (int)fminf(fmaxf(rintf(v.z / scale), -127.0f), 127.0f);
  int q3 = (int)fminf(fmaxf(rintf(v.w / scale), -127.0f), 127.0f);
  unsigned int p = (unsigned int)(q0 & 255) | ((unsigned int)(q1 & 255) << 8) |
                   ((unsigned int)(q2 & 255) << 16) |
                   ((unsigned int)(q3 & 255) << 24);
  qx[i] = (int)p;
}

// ---------------- 3) pack int32 weights -> int8 ----------------
__global__ void pack_w_kernel(const int* __restrict__ w,
                              int* __restrict__ qw, int n4) {
  int i = blockIdx.x * blockDim.x + threadIdx.x;
  if (i >= n4) return;
  int4 v = ((const int4*)w)[i];
  unsigned int p = (unsigned int)(v.x & 255) | ((unsigned int)(v.y & 255) << 8) |
                   ((unsigned int)(v.z & 255) << 16) |
                   ((unsigned int)(v.w & 255) << 24);
  qw[i] = (int)p;
}

// ---------------- 4) int8 GEMM: out[t][o] = sum_k A[t][k]*B[o][k] ----------
// m97 structure: 128x128 tile, BK=64, 256 thr = 4 waves (2x2), each wave 64x64
// = 4x4 grid of 16x16x64 i8 MFMA. global_load_lds width-16 staging.
__global__ __launch_bounds__(256) void gemm_i8_kernel(
    const signed char* __restrict__ A,   // [T][K] int8, K contiguous
    const signed char* __restrict__ B,   // [N][K] int8, K contiguous
    const float* __restrict__ bias,
    const unsigned int* __restrict__ max_bits,
    const float* __restrict__ wscale,
    float* __restrict__ out, int K, int N) {
  __shared__ signed char As[128 * 64];
  __shared__ signed char Bs[128 * 64];

  const int tid = threadIdx.x;
  const int lane = tid & 63;
  const int wid = tid >> 6;
  const int row0 = blockIdx.y * 128;
  const int col0 = blockIdx.x * 128;
  const int wm = (wid >> 1) * 64;  // wave row offset in tile
  const int wn = (wid & 1) * 64;   // wave col offset in tile

  int4v acc[4][4] = {};

  // staging: wave w fills LDS bytes [w*2048, w*2048+2048) in 2 rounds of 1024.
  // lane l -> wave-relative LDS off l*16 -> row = l>>2 (64B rows), k = (l&3)*16
  signed char* lA = As + wid * 2048;
  signed char* lB = Bs + wid * 2048;
  const signed char* gA =
      A + (long)(row0 + wid * 32 + (lane >> 2)) * K + (lane & 3) * 16;
  const signed char* gB =
      B + (long)(col0 + wid * 32 + (lane >> 2)) * K + (lane & 3) * 16;

  // fragment read addresses: A[m=lane&15][k=(lane>>4)*16 + j]  (16B/lane)
  const int fa = (wm + (lane & 15)) * 64 + (lane >> 4) * 16;
  const int fb = (wn + (lane & 15)) * 64 + (lane >> 4) * 16;

  for (int k0 = 0; k0 < K; k0 += 64) {
    __syncthreads();  // LDS reads of prev iter done before overwrite
    async_ld16(gA, lA);
    async_ld16(gA + 16 * (long)K, lA + 1024);
    async_ld16(gB, lB);
    async_ld16(gB + 16 * (long)K, lB + 1024);
    gA += 64;
    gB += 64;
    asm volatile("s_waitcnt vmcnt(0)" ::: "memory");
    __syncthreads();

    int4v a[4], b[4];
#pragma unroll
    for (int i = 0; i < 4; i++) {
      a[i] = *(const int4v*)(As + fa + i * 16 * 64);
      b[i] = *(const int4v*)(Bs + fb + i * 16 * 64);
    }
#pragma unroll
    for (int i = 0; i < 4; i++)
#pragma unroll
      for (int j = 0; j < 4; j++)
        acc[i][j] =
            __builtin_amdgcn_mfma_i32_16x16x64_i8(a[i], b[j], acc[i][j], 0, 0, 0);
  }

  // epilogue: dequant + bias. C/D: col = lane&15, row = (lane>>4)*4 + reg
  const float s = (__uint_as_float(*max_bits) / 127.0f) * wscale[0];
  const int orow = row0 + wm + ((lane >> 4) << 2);
  const int ocol0 = col0 + wn + (lane & 15);
#pragma unroll
  for (int j = 0; j < 4; j++) {
    const int c = ocol0 + j * 16;
    const float bv = bias[c];
#pragma unroll
    for (int i = 0; i < 4; i++) {
#pragma unroll
      for (int r = 0; r < 4; r++) {
        out[(long)(orow + i * 16 + r) * N + c] = (float)acc[i][j][r] * s + bv;
      }
    }
  }
}

extern "C" void kernel_launch(void* const* d_in, const int* in_sizes, int n_in,
                              void* d_out, int out_size, void* d_ws,
                              size_t ws_size, hipStream_t stream) {
  const float* x = (const float*)d_in[0];
  const int* w = (const int*)d_in[1];
  const float* wscale = (const float*)d_in[2];
  const float* bias = (const float*)d_in[3];
  float* out = (float*)d_out;

  const int OUT_F = in_sizes[3];
  const int IN_F = in_sizes[1] / OUT_F;
  const int TOKENS = in_sizes[0] / IN_F;

  unsigned int* max_bits = (unsigned int*)d_ws;
  signed char* qx = (signed char*)d_ws + 256;
  signed char* qw = qx + (size_t)TOKENS * IN_F;

  // ws is poisoned 0xAA before every timed launch -> zero the max slot
  hipMemsetAsync(d_ws, 0, 256, stream);

  const int nx4 = TOKENS * IN_F / 4;
  absmax_kernel<<<1024, 256, 0, stream>>>(x, max_bits, nx4);
  quant_x_kernel<<<(nx4 + 255) / 256, 256, 0, stream>>>(x, max_bits, (int*)qx,
                                                        nx4);
  const int nw4 = OUT_F * IN_F / 4;
  pack_w_kernel<<<(nw4 + 255) / 256, 256, 0, stream>>>(w, (int*)qw, nw4);

  dim3 grid(OUT_F / 128, TOKENS / 128);
  gemm_i8_kernel<<<grid, 256, 0, stream>>>(qx, qw, bias, max_bits, wscale, out,
                                           IN_F, OUT_F);
}

// Round 2
// 284.797 us; speedup vs baseline: 1.0316x; 1.0316x over previous
//
#include <hip/hip_runtime.h>

typedef __attribute__((ext_vector_type(4))) int int4v;

#define NB_MAX 1024  // partial-max array length

// --- async global->LDS, 16B per lane, wave-uniform LDS base ---
__device__ __forceinline__ void async_ld16(const void* g, void* l) {
  __builtin_amdgcn_global_load_lds(
      (const __attribute__((address_space(1))) void*)g,
      (__attribute__((address_space(3))) void*)l,
      16, 0, 0);
}

// ---------------- 1) absmax partials over x (no atomics, no memset) --------
__global__ void absmax_partial_kernel(const float* __restrict__ x,
                                      float* __restrict__ partial, int n4) {
  const float4* x4 = (const float4*)x;
  float m = 0.0f;
  for (int i = blockIdx.x * blockDim.x + threadIdx.x; i < n4;
       i += gridDim.x * blockDim.x) {
    float4 v = x4[i];
    m = fmaxf(m, fabsf(v.x));
    m = fmaxf(m, fabsf(v.y));
    m = fmaxf(m, fabsf(v.z));
    m = fmaxf(m, fabsf(v.w));
  }
#pragma unroll
  for (int off = 32; off > 0; off >>= 1)
    m = fmaxf(m, __shfl_down(m, off, 64));
  __shared__ float wmax[4];
  const int wid = threadIdx.x >> 6;
  if ((threadIdx.x & 63) == 0) wmax[wid] = m;
  __syncthreads();
  if (threadIdx.x == 0)
    partial[blockIdx.x] =
        fmaxf(fmaxf(wmax[0], wmax[1]), fmaxf(wmax[2], wmax[3]));
}

// block-wide reduce of the 1024 partials (every block recomputes; ~L2 hits)
__device__ __forceinline__ float reduce_partials(const float* partial) {
  __shared__ float smax;
  float m = 0.0f;
  for (int i = threadIdx.x; i < NB_MAX; i += blockDim.x)
    m = fmaxf(m, partial[i]);
#pragma unroll
  for (int off = 32; off > 0; off >>= 1)
    m = fmaxf(m, __shfl_down(m, off, 64));
  __shared__ float wmax[4];
  const int wid = threadIdx.x >> 6;
  if ((threadIdx.x & 63) == 0) wmax[wid] = m;
  __syncthreads();
  if (threadIdx.x == 0)
    smax = fmaxf(fmaxf(wmax[0], wmax[1]), fmaxf(wmax[2], wmax[3]));
  __syncthreads();
  return smax;
}

// ---------------- 2) fused: quantize x -> int8  AND  pack w -> int8 -------
__global__ void quant_pack_kernel(const float* __restrict__ x,
                                  const int* __restrict__ w,
                                  const float* __restrict__ partial,
                                  float* __restrict__ scale_slot,
                                  int* __restrict__ qx, int* __restrict__ qw,
                                  int nx4, int nw4) {
  const float scale = reduce_partials(partial) / 127.0f;
  const int i = blockIdx.x * blockDim.x + threadIdx.x;
  if (i == 0) *scale_slot = scale;  // benign same-value race if multiple wrote
  if (i < nx4) {
    float4 v = ((const float4*)x)[i];
    // IEEE division + rint (half-to-even) matches jnp.round(t/scale)
    int q0 = (int)fminf(fmaxf(rintf(v.x / scale), -127.0f), 127.0f);
    int q1 = (int)fminf(fmaxf(rintf(v.y / scale), -127.0f), 127.0f);
    int q2 = (int)fminf(fmaxf(rintf(v.z / scale), -127.0f), 127.0f);
    int q3 = (int)fminf(fmaxf(rintf(v.w / scale), -127.0f), 127.0f);
    unsigned int p = (unsigned int)(q0 & 255) |
                     ((unsigned int)(q1 & 255) << 8) |
                     ((unsigned int)(q2 & 255) << 16) |
                     ((unsigned int)(q3 & 255) << 24);
    qx[i] = (int)p;
  }
  if (i < nw4) {
    int4 v = ((const int4*)w)[i];
    unsigned int p = (unsigned int)(v.x & 255) |
                     ((unsigned int)(v.y & 255) << 8) |
                     ((unsigned int)(v.z & 255) << 16) |
                     ((unsigned int)(v.w & 255) << 24);
    qw[i] = (int)p;
  }
}

// ---------------- 3) int8 GEMM: out[t][o] = sum_k A[t][k]*B[o][k] ----------
// 128x128 tile, BK=64, 4 waves (2x2), each wave 64x64 = 4x4 of 16x16x64 i8.
// LDS k-blocks XOR-swizzled by row: LDS[r][kb] = global kblock kb ^ ((r>>1)&3)
// -> ds_read_b128 start banks spread over 8 positions (2-way = free).
__global__ __launch_bounds__(256) void gemm_i8_kernel(
    const signed char* __restrict__ A,   // [T][K] int8
    const signed char* __restrict__ B,   // [N][K] int8
    const float* __restrict__ bias,
    const float* __restrict__ scale_slot,
    const float* __restrict__ wscale,
    float* __restrict__ out, int K, int N) {
  __shared__ signed char As[128 * 64];
  __shared__ signed char Bs[128 * 64];

  const int tid = threadIdx.x;
  const int lane = tid & 63;
  const int wid = tid >> 6;
  const int row0 = blockIdx.y * 128;
  const int col0 = blockIdx.x * 128;
  const int wm = (wid >> 1) * 64;
  const int wn = (wid & 1) * 64;

  int4v acc[4][4] = {};

  // staging: lane l writes LDS off l*16 (forced). r = l>>2, kb = l&3.
  // load global k-block kb ^ ((r>>1)&3) = (l&3) ^ ((l>>3)&3).
  signed char* lA = As + wid * 2048;
  signed char* lB = Bs + wid * 2048;
  const int kb_s = ((lane & 3) ^ ((lane >> 3) & 3)) * 16;
  const signed char* gA =
      A + (long)(row0 + wid * 32 + (lane >> 2)) * K + kb_s;
  const signed char* gB =
      B + (long)(col0 + wid * 32 + (lane >> 2)) * K + kb_s;

  // fragment reads: row m = lane&15, want global q = lane>>4
  // -> LDS kb = q ^ ((m>>1)&3)
  const int swz_f = (lane >> 1) & 3;
  const int fa = (wm + (lane & 15)) * 64 + (((lane >> 4) ^ swz_f) << 4);
  const int fb = (wn + (lane & 15)) * 64 + (((lane >> 4) ^ swz_f) << 4);

  for (int k0 = 0; k0 < K; k0 += 64) {
    __syncthreads();  // prev-iter LDS reads done before overwrite
    async_ld16(gA, lA);
    async_ld16(gA + 16 * (long)K, lA + 1024);
    async_ld16(gB, lB);
    async_ld16(gB + 16 * (long)K, lB + 1024);
    gA += 64;
    gB += 64;
    asm volatile("s_waitcnt vmcnt(0)" ::: "memory");
    __syncthreads();

    int4v a[4], b[4];
#pragma unroll
    for (int i = 0; i < 4; i++) {
      a[i] = *(const int4v*)(As + fa + i * 16 * 64);
      b[i] = *(const int4v*)(Bs + fb + i * 16 * 64);
    }
#pragma unroll
    for (int i = 0; i < 4; i++)
#pragma unroll
      for (int j = 0; j < 4; j++)
        acc[i][j] =
            __builtin_amdgcn_mfma_i32_16x16x64_i8(a[i], b[j], acc[i][j], 0, 0, 0);
  }

  // epilogue: dequant + bias. C/D: col = lane&15, row = (lane>>4)*4 + reg
  const float s = scale_slot[0] * wscale[0];
  const int orow = row0 + wm + ((lane >> 4) << 2);
  const int ocol0 = col0 + wn + (lane & 15);
#pragma unroll
  for (int j = 0; j < 4; j++) {
    const int c = ocol0 + j * 16;
    const float bv = bias[c];
#pragma unroll
    for (int i = 0; i < 4; i++) {
#pragma unroll
      for (int r = 0; r < 4; r++) {
        out[(long)(orow + i * 16 + r) * N + c] = (float)acc[i][j][r] * s + bv;
      }
    }
  }
}

extern "C" void kernel_launch(void* const* d_in, const int* in_sizes, int n_in,
                              void* d_out, int out_size, void* d_ws,
                              size_t ws_size, hipStream_t stream) {
  const float* x = (const float*)d_in[0];
  const int* w = (const int*)d_in[1];
  const float* wscale = (const float*)d_in[2];
  const float* bias = (const float*)d_in[3];
  float* out = (float*)d_out;

  const int OUT_F = in_sizes[3];
  const int IN_F = in_sizes[1] / OUT_F;
  const int TOKENS = in_sizes[0] / IN_F;

  float* partial = (float*)d_ws;                       // 1024 floats
  float* scale_slot = partial + NB_MAX;                // 1 float
  signed char* qx = (signed char*)d_ws + 8192;
  signed char* qw = qx + (size_t)TOKENS * IN_F;

  const int nx4 = TOKENS * IN_F / 4;
  const int nw4 = OUT_F * IN_F / 4;

  absmax_partial_kernel<<<NB_MAX, 256, 0, stream>>>(x, partial, nx4);

  const int nmax = nx4 > nw4 ? nx4 : nw4;
  quant_pack_kernel<<<(nmax + 255) / 256, 256, 0, stream>>>(
      x, w, partial, scale_slot, (int*)qx, (int*)qw, nx4, nw4);

  dim3 grid(OUT_F / 128, TOKENS / 128);
  gemm_i8_kernel<<<grid, 256, 0, stream>>>(qx, qw, bias, scale_slot, wscale,
                                           out, IN_F, OUT_F);
}

// Round 3
// 281.067 us; speedup vs baseline: 1.0453x; 1.0133x over previous
//
#include <hip/hip_runtime.h>

typedef __attribute__((ext_vector_type(4))) int int4v;

#define NB_MAX 1024  // partial-max array length

// --- async global->LDS, 16B per lane, wave-uniform LDS base ---
__device__ __forceinline__ void async_ld16(const void* g, void* l) {
  __builtin_amdgcn_global_load_lds(
      (const __attribute__((address_space(1))) void*)g,
      (__attribute__((address_space(3))) void*)l,
      16, 0, 0);
}

// ---------------- 1) absmax partials over x (no atomics, no memset) --------
__global__ void absmax_partial_kernel(const float* __restrict__ x,
                                      float* __restrict__ partial, int n4) {
  const float4* x4 = (const float4*)x;
  float m = 0.0f;
  for (int i = blockIdx.x * blockDim.x + threadIdx.x; i < n4;
       i += gridDim.x * blockDim.x) {
    float4 v = x4[i];
    m = fmaxf(m, fabsf(v.x));
    m = fmaxf(m, fabsf(v.y));
    m = fmaxf(m, fabsf(v.z));
    m = fmaxf(m, fabsf(v.w));
  }
#pragma unroll
  for (int off = 32; off > 0; off >>= 1)
    m = fmaxf(m, __shfl_down(m, off, 64));
  __shared__ float wmax[4];
  const int wid = threadIdx.x >> 6;
  if ((threadIdx.x & 63) == 0) wmax[wid] = m;
  __syncthreads();
  if (threadIdx.x == 0)
    partial[blockIdx.x] =
        fmaxf(fmaxf(wmax[0], wmax[1]), fmaxf(wmax[2], wmax[3]));
}

// block-wide reduce of the 1024 partials (every block recomputes; ~L2 hits)
__device__ __forceinline__ float reduce_partials(const float* partial) {
  __shared__ float smax;
  float m = 0.0f;
  for (int i = threadIdx.x; i < NB_MAX; i += blockDim.x)
    m = fmaxf(m, partial[i]);
#pragma unroll
  for (int off = 32; off > 0; off >>= 1)
    m = fmaxf(m, __shfl_down(m, off, 64));
  __shared__ float wmax[4];
  const int wid = threadIdx.x >> 6;
  if ((threadIdx.x & 63) == 0) wmax[wid] = m;
  __syncthreads();
  if (threadIdx.x == 0)
    smax = fmaxf(fmaxf(wmax[0], wmax[1]), fmaxf(wmax[2], wmax[3]));
  __syncthreads();
  return smax;
}

// ---------------- 2) fused: quantize x -> int8  AND  pack w -> int8 -------
__global__ void quant_pack_kernel(const float* __restrict__ x,
                                  const int* __restrict__ w,
                                  const float* __restrict__ partial,
                                  float* __restrict__ scale_slot,
                                  int* __restrict__ qx, int* __restrict__ qw,
                                  int nx4, int nw4) {
  const float scale = reduce_partials(partial) / 127.0f;
  const int i = blockIdx.x * blockDim.x + threadIdx.x;
  if (i == 0) *scale_slot = scale;  // benign same-value race if multiple wrote
  if (i < nx4) {
    float4 v = ((const float4*)x)[i];
    // IEEE division + rint (half-to-even) matches jnp.round(t/scale)
    int q0 = (int)fminf(fmaxf(rintf(v.x / scale), -127.0f), 127.0f);
    int q1 = (int)fminf(fmaxf(rintf(v.y / scale), -127.0f), 127.0f);
    int q2 = (int)fminf(fmaxf(rintf(v.z / scale), -127.0f), 127.0f);
    int q3 = (int)fminf(fmaxf(rintf(v.w / scale), -127.0f), 127.0f);
    unsigned int p = (unsigned int)(q0 & 255) |
                     ((unsigned int)(q1 & 255) << 8) |
                     ((unsigned int)(q2 & 255) << 16) |
                     ((unsigned int)(q3 & 255) << 24);
    qx[i] = (int)p;
  }
  if (i < nw4) {
    int4 v = ((const int4*)w)[i];
    unsigned int p = (unsigned int)(v.x & 255) |
                     ((unsigned int)(v.y & 255) << 8) |
                     ((unsigned int)(v.z & 255) << 16) |
                     ((unsigned int)(v.w & 255) << 24);
    qw[i] = (int)p;
  }
}

// ---------------- 3) int8 GEMM: out[t][o] = sum_k A[t][k]*B[o][k] ----------
// 128x128 tile, BK=64, 4 waves (2x2), each wave 64x64 = 4x4 of 16x16x64 i8.
// DOUBLE-BUFFERED: each tile's global_load_lds is issued one full
// compute-phase before the barrier that drains it (hides load latency that
// round-2 counters showed as ~44% idle). XOR swizzle keeps bank conflicts 0.
__global__ __launch_bounds__(256) void gemm_i8_kernel(
    const signed char* __restrict__ A,   // [T][K] int8
    const signed char* __restrict__ B,   // [N][K] int8
    const float* __restrict__ bias,
    const float* __restrict__ scale_slot,
    const float* __restrict__ wscale,
    float* __restrict__ out, int K, int N) {
  __shared__ signed char As[2][128 * 64];
  __shared__ signed char Bs[2][128 * 64];

  const int tid = threadIdx.x;
  const int lane = tid & 63;
  const int wid = tid >> 6;
  const int row0 = blockIdx.y * 128;
  const int col0 = blockIdx.x * 128;
  const int wm = (wid >> 1) * 64;
  const int wn = (wid & 1) * 64;

  int4v acc[4][4] = {};

  // staging: lane l writes LDS off l*16 (forced). r = l>>2, kb = l&3.
  // load global k-block kb ^ ((r>>1)&3) = (l&3) ^ ((l>>3)&3).
  const int kb_s = ((lane & 3) ^ ((lane >> 3) & 3)) * 16;
  const signed char* gA0 =
      A + (long)(row0 + wid * 32 + (lane >> 2)) * K + kb_s;
  const signed char* gA1 = gA0 + 16 * (long)K;
  const signed char* gB0 =
      B + (long)(col0 + wid * 32 + (lane >> 2)) * K + kb_s;
  const signed char* gB1 = gB0 + 16 * (long)K;
  const int ldsw = wid * 2048;

  // fragment reads: row m = lane&15, global q = lane>>4 -> LDS kb = q ^ swz
  const int swz_f = (lane >> 1) & 3;
  const int fa = (wm + (lane & 15)) * 64 + (((lane >> 4) ^ swz_f) << 4);
  const int fb = (wn + (lane & 15)) * 64 + (((lane >> 4) ^ swz_f) << 4);

  // prologue: tile 0 -> buf 0
  async_ld16(gA0, &As[0][ldsw]);
  async_ld16(gA1, &As[0][ldsw + 1024]);
  async_ld16(gB0, &Bs[0][ldsw]);
  async_ld16(gB1, &Bs[0][ldsw + 1024]);
  int koff = 64;

#define PREFETCH(buf)                                   \
  {                                                     \
    const int ko = (koff < K) ? koff : 0;               \
    async_ld16(gA0 + ko, &As[buf][ldsw]);               \
    async_ld16(gA1 + ko, &As[buf][ldsw + 1024]);        \
    async_ld16(gB0 + ko, &Bs[buf][ldsw]);               \
    async_ld16(gB1 + ko, &Bs[buf][ldsw + 1024]);        \
    koff += 64;                                         \
  }

#define STEP(buf)                                               \
  {                                                             \
    int4v a[4], b[4];                                           \
    _Pragma("unroll") for (int i = 0; i < 4; i++) {             \
      a[i] = *(const int4v*)(&As[buf][fa + i * 16 * 64]);       \
      b[i] = *(const int4v*)(&Bs[buf][fb + i * 16 * 64]);       \
    }                                                           \
    _Pragma("unroll") for (int i = 0; i < 4; i++)               \
        _Pragma("unroll") for (int j = 0; j < 4; j++) acc[i][j] = \
        __builtin_amdgcn_mfma_i32_16x16x64_i8(a[i], b[j], acc[i][j], 0, 0, 0); \
  }

  for (int k0 = 0; k0 < K; k0 += 128) {
    __syncthreads();   // buf0 loads landed; all waves done reading buf1
    PREFETCH(1)        // tile k0+64 -> buf1 (in flight during STEP(0))
    STEP(0)
    __syncthreads();   // buf1 loads landed; all waves done reading buf0
    PREFETCH(0)        // tile k0+128 -> buf0 (in flight during STEP(1))
    STEP(1)
  }
#undef PREFETCH
#undef STEP

  // epilogue: dequant + bias. C/D: col = lane&15, row = (lane>>4)*4 + reg
  const float s = scale_slot[0] * wscale[0];
  const int orow = row0 + wm + ((lane >> 4) << 2);
  const int ocol0 = col0 + wn + (lane & 15);
#pragma unroll
  for (int j = 0; j < 4; j++) {
    const int c = ocol0 + j * 16;
    const float bv = bias[c];
#pragma unroll
    for (int i = 0; i < 4; i++) {
#pragma unroll
      for (int r = 0; r < 4; r++) {
        out[(long)(orow + i * 16 + r) * N + c] = (float)acc[i][j][r] * s + bv;
      }
    }
  }
}

extern "C" void kernel_launch(void* const* d_in, const int* in_sizes, int n_in,
                              void* d_out, int out_size, void* d_ws,
                              size_t ws_size, hipStream_t stream) {
  const float* x = (const float*)d_in[0];
  const int* w = (const int*)d_in[1];
  const float* wscale = (const float*)d_in[2];
  const float* bias = (const float*)d_in[3];
  float* out = (float*)d_out;

  const int OUT_F = in_sizes[3];
  const int IN_F = in_sizes[1] / OUT_F;
  const int TOKENS = in_sizes[0] / IN_F;

  float* partial = (float*)d_ws;                       // 1024 floats
  float* scale_slot = partial + NB_MAX;                // 1 float
  signed char* qx = (signed char*)d_ws + 8192;
  signed char* qw = qx + (size_t)TOKENS * IN_F;

  const int nx4 = TOKENS * IN_F / 4;
  const int nw4 = OUT_F * IN_F / 4;

  absmax_partial_kernel<<<NB_MAX, 256, 0, stream>>>(x, partial, nx4);

  const int nmax = nx4 > nw4 ? nx4 : nw4;
  quant_pack_kernel<<<(nmax + 255) / 256, 256, 0, stream>>>(
      x, w, partial, scale_slot, (int*)qx, (int*)qw, nx4, nw4);

  dim3 grid(OUT_F / 128, TOKENS / 128);
  gemm_i8_kernel<<<grid, 256, 0, stream>>>(qx, qw, bias, scale_slot, wscale,
                                           out, IN_F, OUT_F);
}

// Round 4
// 259.224 us; speedup vs baseline: 1.1334x; 1.0843x over previous
//
#include <hip/hip_runtime.h>

typedef __attribute__((ext_vector_type(4))) int int4v;

#define NB_MAX 1024  // partial-max array length

// --- async global->LDS, 16B per lane, wave-uniform LDS base ---
__device__ __forceinline__ void async_ld16(const void* g, void* l) {
  __builtin_amdgcn_global_load_lds(
      (const __attribute__((address_space(1))) void*)g,
      (__attribute__((address_space(3))) void*)l,
      16, 0, 0);
}

// ---------------- 1) absmax partials over x (no atomics, no memset) --------
__global__ void absmax_partial_kernel(const float* __restrict__ x,
                                      float* __restrict__ partial, int n4) {
  const float4* x4 = (const float4*)x;
  float m = 0.0f;
  for (int i = blockIdx.x * blockDim.x + threadIdx.x; i < n4;
       i += gridDim.x * blockDim.x) {
    float4 v = x4[i];
    m = fmaxf(m, fabsf(v.x));
    m = fmaxf(m, fabsf(v.y));
    m = fmaxf(m, fabsf(v.z));
    m = fmaxf(m, fabsf(v.w));
  }
#pragma unroll
  for (int off = 32; off > 0; off >>= 1)
    m = fmaxf(m, __shfl_down(m, off, 64));
  __shared__ float wmax[4];
  const int wid = threadIdx.x >> 6;
  if ((threadIdx.x & 63) == 0) wmax[wid] = m;
  __syncthreads();
  if (threadIdx.x == 0)
    partial[blockIdx.x] =
        fmaxf(fmaxf(wmax[0], wmax[1]), fmaxf(wmax[2], wmax[3]));
}

// block-wide reduce of the 1024 partials (every block recomputes; ~L2 hits)
__device__ __forceinline__ float reduce_partials(const float* partial) {
  __shared__ float smax;
  float m = 0.0f;
  for (int i = threadIdx.x; i < NB_MAX; i += blockDim.x)
    m = fmaxf(m, partial[i]);
#pragma unroll
  for (int off = 32; off > 0; off >>= 1)
    m = fmaxf(m, __shfl_down(m, off, 64));
  __shared__ float wmax[4];
  const int wid = threadIdx.x >> 6;
  if ((threadIdx.x & 63) == 0) wmax[wid] = m;
  __syncthreads();
  if (threadIdx.x == 0)
    smax = fmaxf(fmaxf(wmax[0], wmax[1]), fmaxf(wmax[2], wmax[3]));
  __syncthreads();
  return smax;
}

// ---------------- 2) fused: quantize x -> int8  AND  pack w -> int8 -------
__global__ void quant_pack_kernel(const float* __restrict__ x,
                                  const int* __restrict__ w,
                                  const float* __restrict__ partial,
                                  float* __restrict__ scale_slot,
                                  int* __restrict__ qx, int* __restrict__ qw,
                                  int nx4, int nw4) {
  const float scale = reduce_partials(partial) / 127.0f;
  const int i = blockIdx.x * blockDim.x + threadIdx.x;
  if (i == 0) *scale_slot = scale;  // benign same-value race if multiple wrote
  if (i < nx4) {
    float4 v = ((const float4*)x)[i];
    // IEEE division + rint (half-to-even) matches jnp.round(t/scale)
    int q0 = (int)fminf(fmaxf(rintf(v.x / scale), -127.0f), 127.0f);
    int q1 = (int)fminf(fmaxf(rintf(v.y / scale), -127.0f), 127.0f);
    int q2 = (int)fminf(fmaxf(rintf(v.z / scale), -127.0f), 127.0f);
    int q3 = (int)fminf(fmaxf(rintf(v.w / scale), -127.0f), 127.0f);
    unsigned int p = (unsigned int)(q0 & 255) |
                     ((unsigned int)(q1 & 255) << 8) |
                     ((unsigned int)(q2 & 255) << 16) |
                     ((unsigned int)(q3 & 255) << 24);
    qx[i] = (int)p;
  }
  if (i < nw4) {
    int4 v = ((const int4*)w)[i];
    unsigned int p = (unsigned int)(v.x & 255) |
                     ((unsigned int)(v.y & 255) << 8) |
                     ((unsigned int)(v.z & 255) << 16) |
                     ((unsigned int)(v.w & 255) << 24);
    qw[i] = (int)p;
  }
}

// ---------------- 3) int8 GEMM: out[t][o] = sum_k A[t][k]*B[o][k] ----------
// m97-granularity structure: 128x128 tile, BK=128 BYTES, single-buffered.
// 4 waves (2x2), each wave 64x64 = 4x4 accs of 16x16x64 i8; 32 MFMAs +
// 16 ds_read_b128 per wave per barrier (2x round-3's granularity, half the
// barrier/drain events). LDS rows = 128 B (8 chunks of 16 B); chunk XOR-
// swizzled by row&7 so every ds_read_b128 spreads 8 lanes uniformly on each
// of the 8 column windows (conflict-free), and staging stays lane-contiguous.
__global__ __launch_bounds__(256) void gemm_i8_kernel(
    const signed char* __restrict__ A,   // [T][K] int8
    const signed char* __restrict__ B,   // [N][K] int8
    const float* __restrict__ bias,
    const float* __restrict__ scale_slot,
    const float* __restrict__ wscale,
    float* __restrict__ out, int K, int N) {
  __shared__ signed char As[128 * 128];
  __shared__ signed char Bs[128 * 128];

  const int tid = threadIdx.x;
  const int lane = tid & 63;
  const int wid = tid >> 6;
  const int row0 = blockIdx.y * 128;
  const int col0 = blockIdx.x * 128;
  const int wm = (wid >> 1) * 64;
  const int wn = (wid & 1) * 64;

  int4v acc[4][4] = {};

  // --- staging: per round of 1 KB, lane l covers row (l>>3), LDS chunk l&7.
  // LDS chunk c of row r holds global chunk c ^ (r&7):
  //   lane loads global chunk (l&7) ^ ((l>>3)&7).
  const int gchunk = ((lane & 7) ^ ((lane >> 3) & 7)) * 16;
  const signed char* gA =
      A + (long)(row0 + wid * 32 + (lane >> 3)) * K + gchunk;
  const signed char* gB =
      B + (long)(col0 + wid * 32 + (lane >> 3)) * K + gchunk;
  const int ldsw = wid * 4096;  // wave's 4 KB stripe (32 rows)

  // --- fragment reads: row m = wm + i*16 + (lane&15); global chunk for
  // k-step s is s*4 + (lane>>4); LDS chunk = that ^ (row&7) = ^ (lane&7).
  const int q = lane >> 4;
  const int c7 = lane & 7;
  const int frow = (wm + (lane & 15)) * 128;
  const int fcs0 = ((q ^ c7) << 4);        // k-step 0 chunk offset
  const int fcs1 = (((4 + q) ^ c7) << 4);  // k-step 1 chunk offset
  const int fbrow = (wn + (lane & 15)) * 128;

  for (int k0 = 0; k0 < K; k0 += 128) {
    __syncthreads();  // prev-iter LDS reads done before overwrite
#pragma unroll
    for (int t = 0; t < 4; t++) {
      async_ld16(gA + k0 + t * 8 * (long)K, As + ldsw + t * 1024);
      async_ld16(gB + k0 + t * 8 * (long)K, Bs + ldsw + t * 1024);
    }
    asm volatile("s_waitcnt vmcnt(0)" ::: "memory");
    __syncthreads();

#pragma unroll
    for (int s = 0; s < 2; s++) {
      const int ca = (s == 0) ? fcs0 : fcs1;
      int4v a[4], b[4];
#pragma unroll
      for (int i = 0; i < 4; i++) {
        a[i] = *(const int4v*)(As + frow + i * 16 * 128 + ca);
        b[i] = *(const int4v*)(Bs + fbrow + i * 16 * 128 + ca);
      }
#pragma unroll
      for (int i = 0; i < 4; i++)
#pragma unroll
        for (int j = 0; j < 4; j++)
          acc[i][j] = __builtin_amdgcn_mfma_i32_16x16x64_i8(a[i], b[j],
                                                            acc[i][j], 0, 0, 0);
    }
  }

  // epilogue: dequant + bias. C/D: col = lane&15, row = (lane>>4)*4 + reg
  const float s = scale_slot[0] * wscale[0];
  const int orow = row0 + wm + ((lane >> 4) << 2);
  const int ocol0 = col0 + wn + (lane & 15);
#pragma unroll
  for (int j = 0; j < 4; j++) {
    const int c = ocol0 + j * 16;
    const float bv = bias[c];
#pragma unroll
    for (int i = 0; i < 4; i++) {
#pragma unroll
      for (int r = 0; r < 4; r++) {
        out[(long)(orow + i * 16 + r) * N + c] = (float)acc[i][j][r] * s + bv;
      }
    }
  }
}

extern "C" void kernel_launch(void* const* d_in, const int* in_sizes, int n_in,
                              void* d_out, int out_size, void* d_ws,
                              size_t ws_size, hipStream_t stream) {
  const float* x = (const float*)d_in[0];
  const int* w = (const int*)d_in[1];
  const float* wscale = (const float*)d_in[2];
  const float* bias = (const float*)d_in[3];
  float* out = (float*)d_out;

  const int OUT_F = in_sizes[3];
  const int IN_F = in_sizes[1] / OUT_F;
  const int TOKENS = in_sizes[0] / IN_F;

  float* partial = (float*)d_ws;                       // 1024 floats
  float* scale_slot = partial + NB_MAX;                // 1 float
  signed char* qx = (signed char*)d_ws + 8192;
  signed char* qw = qx + (size_t)TOKENS * IN_F;

  const int nx4 = TOKENS * IN_F / 4;
  const int nw4 = OUT_F * IN_F / 4;

  absmax_partial_kernel<<<NB_MAX, 256, 0, stream>>>(x, partial, nx4);

  const int nmax = nx4 > nw4 ? nx4 : nw4;
  quant_pack_kernel<<<(nmax + 255) / 256, 256, 0, stream>>>(
      x, w, partial, scale_slot, (int*)qx, (int*)qw, nx4, nw4);

  dim3 grid(OUT_F / 128, TOKENS / 128);
  gemm_i8_kernel<<<grid, 256, 0, stream>>>(qx, qw, bias, scale_slot, wscale,
                                           out, IN_F, OUT_F);
}